// Round 9
// baseline (671.780 us; speedup 1.0000x reference)
//
#include <hip/hip_runtime.h>
#include <hip/hip_bf16.h>

#define NSUB 4096
#define DIM 64
#define NROW 8192
#define KTOP 20
#define CAND 64        // max survivors per row in filter pass

typedef unsigned long long u64;
typedef __attribute__((ext_vector_type(8))) short bf16x8;   // 8 bf16 = 4 VGPRs
typedef __attribute__((ext_vector_type(4))) float f32x4;

__device__ __forceinline__ unsigned umax(unsigned a, unsigned b) { return a > b ? a : b; }
__device__ __forceinline__ unsigned umin(unsigned a, unsigned b) { return a < b ? a : b; }

// -------------------------------------------------------------------------
// K1: V[k] = emb[k] @ w[k] + b[k], f64 accumulate from f32 inputs.
// Emits f64 row-major (exact refine) + bf16 row-major (MFMA passes).
// Also zeroes cnt[8192] (blocks 0..31) and done[128] (block 32) so the
// memset dispatch disappears. grid 512, block 256.
// -------------------------------------------------------------------------
__global__ __launch_bounds__(256) void k_compute_v(
        const float* __restrict__ emb1, const float* __restrict__ w1,
        const float* __restrict__ b1,
        const float* __restrict__ emb2, const float* __restrict__ w2,
        const float* __restrict__ b2,
        double* __restrict__ V1d, double* __restrict__ V2d,
        unsigned short* __restrict__ V1b, unsigned short* __restrict__ V2b,
        unsigned int* __restrict__ cnt, unsigned int* __restrict__ done) {
    __shared__ alignas(16) float embS[64 * 64];
    __shared__ alignas(16) float wS[64 * 64];
    __shared__ float bS[64];

    int bx    = blockIdx.x;
    int tid   = threadIdx.x;

    // zero the filter-pass counters (visible to later dispatches by stream order)
    if (bx < 32) cnt[bx * 256 + tid] = 0u;
    if (bx == 32 && tid < 128) done[tid] = 0u;

    int which = bx >> 8;
    int rem   = bx & 255;
    int k     = rem >> 6;
    int tile  = rem & 63;
    int n0    = tile * 64;

    const float* emb = which ? emb2 : emb1;
    const float* w   = which ? w2 : w1;
    const float* b   = which ? b2 : b1;
    double* Vd = which ? V2d : V1d;
    unsigned short* Vb = which ? V2b : V1b;

    const float* esrc = emb + ((size_t)k * NSUB + n0) * DIM;
    const float* wsrc = w + (size_t)k * DIM * DIM;
    for (int t = tid; t < 64 * 64; t += 256) { embS[t] = esrc[t]; wS[t] = wsrc[t]; }
    if (tid < 64) bS[tid] = b[k * 64 + tid];
    __syncthreads();

    int e    = tid & 63;
    int mrow = tid >> 6;

    double accs[16];
#pragma unroll
    for (int it = 0; it < 16; ++it) accs[it] = (double)bS[e];

    for (int dg = 0; dg < 16; ++dg) {
        double wv[4];
#pragma unroll
        for (int q = 0; q < 4; ++q) wv[q] = (double)wS[(dg * 4 + q) * 64 + e];
#pragma unroll
        for (int it = 0; it < 16; ++it) {
            float4 em = *(const float4*)&embS[(mrow * 16 + it) * 64 + dg * 4];
            accs[it] += (double)em.x * wv[0] + (double)em.y * wv[1]
                      + (double)em.z * wv[2] + (double)em.w * wv[3];
        }
    }

#pragma unroll
    for (int it = 0; it < 16; ++it) {
        size_t o = ((size_t)k * NSUB + n0 + mrow * 16 + it) * DIM + e;
        Vd[o] = accs[it];
        __hip_bfloat16 hv = __float2bfloat16((float)accs[it]);
        Vb[o] = *reinterpret_cast<unsigned short*>(&hv);
    }
}

// -------------------------------------------------------------------------
// K2 (stage1): per (row, 256-col block) top-2 of relu(scores), in registers.
// wg = 64 rows x 1024 cols: grid 1024 -> 4 wg/CU, 4 waves/SIMD. Each wave:
// 4 A-tiles (4x B reuse), exactly one 256-col block in 16 strips of 16,
// register double-buffered B. Top-2 update = fmax + fmed3 (m1>=m2
// invariant). One butterfly merge after the loop. No LDS, no barriers.
// Output S1[row][32 blocks][2] = f32 bit patterns of block top-2.
// -------------------------------------------------------------------------
__global__ __launch_bounds__(256, 4) void k_stage1(const unsigned short* __restrict__ V1b,
                                                   const unsigned short* __restrict__ V2b,
                                                   unsigned int* __restrict__ S1) {
    int tid = threadIdx.x;
    int l = tid & 63;
    int w = tid >> 6;
    int bx = blockIdx.x;
    int rt = bx >> 3;
    int h  = (bx >> 2) & 1;
    int e8 = bx & 3;
    int r0 = rt * 64;
    int i  = r0 >> 12;
    int n0 = r0 & (NSUB - 1);
    int kb = 2 * i + h;
    int q  = l >> 4;

    bf16x8 a0[4], a1[4];
#pragma unroll
    for (int t = 0; t < 4; ++t) {
        const unsigned short* ap =
            V1b + ((size_t)kb * NSUB + n0 + t * 16 + (l & 15)) * DIM + (q * 8);
        a0[t] = *(const bf16x8*)ap;
        a1[t] = *(const bf16x8*)(ap + 32);
    }

    int coff = e8 * 1024 + w * 256;
    const unsigned short* bp =
        V2b + ((size_t)kb * NSUB + coff + (l & 15)) * DIM + (q * 8);

    float m1[16], m2[16];
#pragma unroll
    for (int sl = 0; sl < 16; ++sl) { m1[sl] = 0.f; m2[sl] = 0.f; }

    bf16x8 cb0 = *(const bf16x8*)bp;
    bf16x8 cb1 = *(const bf16x8*)(bp + 32);
    bp += 16 * DIM;

    for (int s = 0; s < 16; ++s) {
        bf16x8 nb0, nb1;
        if (s < 15) {
            nb0 = *(const bf16x8*)bp;
            nb1 = *(const bf16x8*)(bp + 32);
            bp += 16 * DIM;
        }
#pragma unroll
        for (int t = 0; t < 4; ++t) {
            f32x4 acc = {0.f, 0.f, 0.f, 0.f};
            acc = __builtin_amdgcn_mfma_f32_16x16x32_bf16(a0[t], cb0, acc, 0, 0, 0);
            acc = __builtin_amdgcn_mfma_f32_16x16x32_bf16(a1[t], cb1, acc, 0, 0, 0);
#pragma unroll
            for (int r = 0; r < 4; ++r) {
                int sl = t * 4 + r;
                float v = acc[r];
                m2[sl] = __builtin_amdgcn_fmed3f(v, m1[sl], m2[sl]);
                m1[sl] = fmaxf(m1[sl], v);
            }
        }
        cb0 = nb0; cb1 = nb1;
    }

#pragma unroll
    for (int st = 1; st <= 8; st <<= 1) {
#pragma unroll
        for (int sl = 0; sl < 16; ++sl) {
            float o1 = __shfl_xor(m1[sl], st);
            float o2 = __shfl_xor(m2[sl], st);
            float nm1 = fmaxf(m1[sl], o1);
            float nm2 = fmaxf(fminf(m1[sl], o1), fmaxf(m2[sl], o2));
            m1[sl] = nm1; m2[sl] = nm2;
        }
    }
    if ((l & 15) == 0) {
        int gblk = h * 16 + e8 * 4 + w;
#pragma unroll
        for (int sl = 0; sl < 16; ++sl) {
            int rowg = r0 + (sl >> 2) * 16 + q * 4 + (sl & 3);
            uint2 vv;
            vv.x = __float_as_uint(m1[sl]);
            vv.y = __float_as_uint(m2[sl]);
            *(uint2*)&S1[(size_t)rowg * 64 + gblk * 2] = vv;
        }
    }
}

// -------------------------------------------------------------------------
// K3 (filter + folded threshold + folded refine):
// Phase A: per wg, each wave bitonic-sorts 16 rows' 64 block-top-2 keys
//   from S1 -> Lth (20th largest - margin) in LDS.
// Phase B: recompute scores (same geometry as stage1, double-buffered B),
//   append every value >= Lth[row] via device-scope atomic (~27/row total).
// Phase C gate (R8 bugfix): fence -> __syncthreads() -> publish. The
//   barrier guarantees ALL waves of this wg finished Phase B and fenced
//   before tid0 increments done[rt]; the 8th (last) wg acquires and
//   refines: exact f64 dots (same serial d-order as all passing rounds),
//   rank by (f64 value, lower-col), write top-20 + tanh.
// grid 1024 (= 128 row-tiles x 8 col-eighths), block 256.
// -------------------------------------------------------------------------
__global__ __launch_bounds__(256, 4) void k_filter(const unsigned short* __restrict__ V1b,
                                                   const unsigned short* __restrict__ V2b,
                                                   const unsigned int* __restrict__ S1,
                                                   unsigned int* __restrict__ cnt,
                                                   int* __restrict__ colsG,
                                                   const double* __restrict__ V1d,
                                                   const double* __restrict__ V2d,
                                                   unsigned int* __restrict__ done,
                                                   int* __restrict__ outIdx,
                                                   float* __restrict__ outVal) {
    __shared__ float Lsh[64];
    __shared__ int lastS;
    int tid = threadIdx.x;
    int l = tid & 63;
    int w = tid >> 6;
    int bx = blockIdx.x;
    int rt = bx >> 3;
    int h  = (bx >> 2) & 1;
    int e8 = bx & 3;
    int r0 = rt * 64;
    int i  = r0 >> 12;
    int n0 = r0 & (NSUB - 1);
    int kb = 2 * i + h;
    int q  = l >> 4;

    // ---- Phase A: thresholds (wave w -> rows r0+w*16 .. +15) ----
    for (int rr = 0; rr < 16; ++rr) {
        int rowg = r0 + w * 16 + rr;
        unsigned key = S1[(size_t)rowg * 64 + l];
#pragma unroll
        for (int k = 2; k <= 64; k <<= 1) {
#pragma unroll
            for (int j = k >> 1; j > 0; j >>= 1) {
                unsigned other = (unsigned)__shfl_xor((int)key, j);
                int ixj = l ^ j;
                bool up = ((l & k) == 0);
                bool keepMax = ((l > ixj) == up);
                key = keepMax ? umax(key, other) : umin(key, other);
            }
        }
        // ascending; 20th largest at lane 44
        if (l == 44) Lsh[w * 16 + rr] = fmaxf(__uint_as_float(key) - 0.006f, 1e-30f);
    }
    __syncthreads();

    // ---- Phase B: filter ----
    bf16x8 a0[4], a1[4];
#pragma unroll
    for (int t = 0; t < 4; ++t) {
        const unsigned short* ap =
            V1b + ((size_t)kb * NSUB + n0 + t * 16 + (l & 15)) * DIM + (q * 8);
        a0[t] = *(const bf16x8*)ap;
        a1[t] = *(const bf16x8*)(ap + 32);
    }

    float Lr[16];
#pragma unroll
    for (int sl = 0; sl < 16; ++sl)
        Lr[sl] = Lsh[(sl >> 2) * 16 + q * 4 + (sl & 3)];

    int coff = e8 * 1024 + w * 256;
    const unsigned short* bp =
        V2b + ((size_t)kb * NSUB + coff + (l & 15)) * DIM + (q * 8);

    bf16x8 cb0 = *(const bf16x8*)bp;
    bf16x8 cb1 = *(const bf16x8*)(bp + 32);
    bp += 16 * DIM;

    for (int s = 0; s < 16; ++s) {
        bf16x8 nb0, nb1;
        if (s < 15) {
            nb0 = *(const bf16x8*)bp;
            nb1 = *(const bf16x8*)(bp + 32);
            bp += 16 * DIM;
        }
        int c = h * 4096 + coff + s * 16 + (l & 15);
#pragma unroll
        for (int t = 0; t < 4; ++t) {
            f32x4 acc = {0.f, 0.f, 0.f, 0.f};
            acc = __builtin_amdgcn_mfma_f32_16x16x32_bf16(a0[t], cb0, acc, 0, 0, 0);
            acc = __builtin_amdgcn_mfma_f32_16x16x32_bf16(a1[t], cb1, acc, 0, 0, 0);
#pragma unroll
            for (int r = 0; r < 4; ++r) {
                int sl = t * 4 + r;
                if (acc[r] >= Lr[sl]) {
                    int rowg = r0 + t * 16 + q * 4 + r;
                    unsigned pos = atomicAdd(&cnt[rowg], 1u);
                    if (pos < CAND) colsG[(size_t)rowg * CAND + pos] = c;
                }
            }
        }
        cb0 = nb0; cb1 = nb1;
    }

    // ---- Phase C: last-arriver refine ----
    __threadfence();       // release: make THIS thread's writes device-visible
    __syncthreads();       // ALL waves of this wg have finished Phase B + fenced
    if (tid == 0) lastS = (atomicAdd(&done[rt], 1u) == 7u) ? 1 : 0;
    __syncthreads();
    if (!lastS) return;
    __threadfence();       // acquire: see all 8 wgs' published writes

    for (int rr = 0; rr < 16; ++rr) {
        int row = r0 + w * 16 + rr;
        int n = row & (NSUB - 1);

        unsigned cn = cnt[row];
        if (cn > CAND) cn = CAND;
        bool valid = (unsigned)l < cn;
        int c = valid ? colsG[(size_t)row * CAND + l] : 0;
        int kk2 = 2 * i + (c >> 12);
        int m = c & (NSUB - 1);

        const double* v1p = V1d + ((size_t)kk2 * NSUB + n) * DIM;
        const double* v2p = V2d + ((size_t)kk2 * NSUB + m) * DIM;
        double a = 0.0;
        for (int d = 0; d < DIM; ++d) a += v1p[d] * v2p[d];

        double av = a > 0.0 ? a : 0.0;
        u64 key = (((u64)__double_as_longlong(av)) & ~0x1FFFull) | (u64)(8191 - c);
        if (!valid) key = 0;

        int rank = 0;
        for (int jj = 0; jj < 64; ++jj) {
            u64 kj = (u64)__shfl((long long)key, jj);
            rank += (kj > key || (kj == key && jj < l)) ? 1 : 0;
        }
        if (valid && rank < KTOP) {
            float val = (av > 0.0) ? (float)tanh(3.0 * av) : 0.0f;
            outIdx[(size_t)row * KTOP + rank] = c;
            outVal[(size_t)row * KTOP + rank] = val;
        }
    }
}

// -------------------------------------------------------------------------
// K4: fused zero + scatter. wg owns 4 contiguous rows (128 KB).
// grid 2048 x 256. (unchanged — verified R4-R7)
// -------------------------------------------------------------------------
__global__ __launch_bounds__(256) void k_write(const int* __restrict__ outIdx,
                                               const float* __restrict__ outVal,
                                               float* __restrict__ out) {
    int t = threadIdx.x;
    size_t base = (size_t)blockIdx.x * 4 * NROW;
    float4 z = {0.f, 0.f, 0.f, 0.f};
    float4* o4 = (float4*)(out + base);
#pragma unroll
    for (int it = 0; it < 32; ++it) o4[it * 256 + t] = z;
    __syncthreads();
    if (t < 4 * KTOP) {
        int row = blockIdx.x * 4 + t / KTOP;
        int c = outIdx[(size_t)blockIdx.x * 4 * KTOP + t];
        float v = outVal[(size_t)blockIdx.x * 4 * KTOP + t];
        out[(size_t)row * NROW + c] = v;
    }
}

extern "C" void kernel_launch(void* const* d_in, const int* in_sizes, int n_in,
                              void* d_out, int out_size, void* d_ws, size_t ws_size,
                              hipStream_t stream) {
    // inputs: idx, emb1, emb2, w1, w2, b1, b2
    const float* emb1 = (const float*)d_in[1];
    const float* emb2 = (const float*)d_in[2];
    const float* w1   = (const float*)d_in[3];
    const float* w2   = (const float*)d_in[4];
    const float* b1   = (const float*)d_in[5];
    const float* b2   = (const float*)d_in[6];
    float* out = (float*)d_out;

    // staging in the head of d_out (24 MB of 256 MB); fully consumed by
    // k_filter's refine tail before k_write overwrites everything.
    char* p = (char*)d_out;
    double*         V1d   = (double*)p;                                      // 0..8 MB
    double*         V2d   = (double*)(p + (size_t)8 * 1024 * 1024);          // 8..16 MB
    unsigned short* V1b   = (unsigned short*)(p + (size_t)16 * 1024 * 1024); // 16..18 MB
    unsigned short* V2b   = (unsigned short*)(p + (size_t)18 * 1024 * 1024); // 18..20 MB
    unsigned int*   S1    = (unsigned int*)(p + (size_t)20 * 1024 * 1024);   // 20..22 MB
    int*            colsG = (int*)(p + (size_t)22 * 1024 * 1024);            // 22..24 MB

    int*          outIdx = (int*)d_ws;
    float*        outVal = (float*)((char*)d_ws + (size_t)NROW * KTOP * sizeof(int));
    unsigned int* cntp   = (unsigned int*)((char*)d_ws + (size_t)2 * NROW * KTOP * sizeof(int));
    unsigned int* donep  = cntp + NROW;

    hipLaunchKernelGGL(k_compute_v, dim3(512), dim3(256), 0, stream,
                       emb1, w1, b1, emb2, w2, b2, V1d, V2d, V1b, V2b, cntp, donep);
    hipLaunchKernelGGL(k_stage1, dim3(1024), dim3(256), 0, stream, V1b, V2b, S1);
    hipLaunchKernelGGL(k_filter, dim3(1024), dim3(256), 0, stream,
                       V1b, V2b, S1, cntp, colsG, V1d, V2d, donep, outIdx, outVal);
    hipLaunchKernelGGL(k_write, dim3(2048), dim3(256), 0, stream,
                       outIdx, outVal, out);
}

// Round 10
// 427.332 us; speedup vs baseline: 1.5720x; 1.5720x over previous
//
#include <hip/hip_runtime.h>
#include <hip/hip_bf16.h>

#define NSUB 4096
#define DIM 64
#define NROW 8192
#define KTOP 20
#define CAND 64        // max survivors per row in filter pass

typedef unsigned long long u64;
typedef __attribute__((ext_vector_type(8))) short bf16x8;   // 8 bf16 = 4 VGPRs
typedef __attribute__((ext_vector_type(4))) float f32x4;

__device__ __forceinline__ unsigned umax(unsigned a, unsigned b) { return a > b ? a : b; }
__device__ __forceinline__ unsigned umin(unsigned a, unsigned b) { return a < b ? a : b; }

// -------------------------------------------------------------------------
// K1: V[k] = emb[k] @ w[k] + b[k], f64 accumulate from f32 inputs.
// Emits f64 row-major (exact refine) + bf16 row-major (MFMA passes).
// Also zeroes cnt[8192] (blocks 0..31) so the memset dispatch disappears.
// grid 512, block 256. (verified R3-R9)
// -------------------------------------------------------------------------
__global__ __launch_bounds__(256) void k_compute_v(
        const float* __restrict__ emb1, const float* __restrict__ w1,
        const float* __restrict__ b1,
        const float* __restrict__ emb2, const float* __restrict__ w2,
        const float* __restrict__ b2,
        double* __restrict__ V1d, double* __restrict__ V2d,
        unsigned short* __restrict__ V1b, unsigned short* __restrict__ V2b,
        unsigned int* __restrict__ cnt) {
    __shared__ alignas(16) float embS[64 * 64];
    __shared__ alignas(16) float wS[64 * 64];
    __shared__ float bS[64];

    int bx    = blockIdx.x;
    int tid   = threadIdx.x;

    // zero the filter-pass counters (visible to later dispatches by stream order)
    if (bx < 32) cnt[bx * 256 + tid] = 0u;

    int which = bx >> 8;
    int rem   = bx & 255;
    int k     = rem >> 6;
    int tile  = rem & 63;
    int n0    = tile * 64;

    const float* emb = which ? emb2 : emb1;
    const float* w   = which ? w2 : w1;
    const float* b   = which ? b2 : b1;
    double* Vd = which ? V2d : V1d;
    unsigned short* Vb = which ? V2b : V1b;

    const float* esrc = emb + ((size_t)k * NSUB + n0) * DIM;
    const float* wsrc = w + (size_t)k * DIM * DIM;
    for (int t = tid; t < 64 * 64; t += 256) { embS[t] = esrc[t]; wS[t] = wsrc[t]; }
    if (tid < 64) bS[tid] = b[k * 64 + tid];
    __syncthreads();

    int e    = tid & 63;
    int mrow = tid >> 6;

    double accs[16];
#pragma unroll
    for (int it = 0; it < 16; ++it) accs[it] = (double)bS[e];

    for (int dg = 0; dg < 16; ++dg) {
        double wv[4];
#pragma unroll
        for (int q = 0; q < 4; ++q) wv[q] = (double)wS[(dg * 4 + q) * 64 + e];
#pragma unroll
        for (int it = 0; it < 16; ++it) {
            float4 em = *(const float4*)&embS[(mrow * 16 + it) * 64 + dg * 4];
            accs[it] += (double)em.x * wv[0] + (double)em.y * wv[1]
                      + (double)em.z * wv[2] + (double)em.w * wv[3];
        }
    }

#pragma unroll
    for (int it = 0; it < 16; ++it) {
        size_t o = ((size_t)k * NSUB + n0 + mrow * 16 + it) * DIM + e;
        Vd[o] = accs[it];
        __hip_bfloat16 hv = __float2bfloat16((float)accs[it]);
        Vb[o] = *reinterpret_cast<unsigned short*>(&hv);
    }
}

// -------------------------------------------------------------------------
// K2 (stage1): per (row, 256-col block) top-2 of relu(scores), in registers.
// wg = 64 rows x 1024 cols: grid 1024 -> 4 wg/CU, 4 waves/SIMD. Each wave:
// 4 A-tiles (4x B reuse), exactly one 256-col block in 16 strips of 16,
// register double-buffered B. Top-2 update = fmax + fmed3 (m1>=m2
// invariant). One butterfly merge after the loop. No LDS, no barriers.
// Output S1[row][32 blocks][2] = f32 bit patterns of block top-2.
// (verified R9)
// -------------------------------------------------------------------------
__global__ __launch_bounds__(256, 4) void k_stage1(const unsigned short* __restrict__ V1b,
                                                   const unsigned short* __restrict__ V2b,
                                                   unsigned int* __restrict__ S1) {
    int tid = threadIdx.x;
    int l = tid & 63;
    int w = tid >> 6;
    int bx = blockIdx.x;
    int rt = bx >> 3;
    int h  = (bx >> 2) & 1;
    int e8 = bx & 3;
    int r0 = rt * 64;
    int i  = r0 >> 12;
    int n0 = r0 & (NSUB - 1);
    int kb = 2 * i + h;
    int q  = l >> 4;

    bf16x8 a0[4], a1[4];
#pragma unroll
    for (int t = 0; t < 4; ++t) {
        const unsigned short* ap =
            V1b + ((size_t)kb * NSUB + n0 + t * 16 + (l & 15)) * DIM + (q * 8);
        a0[t] = *(const bf16x8*)ap;
        a1[t] = *(const bf16x8*)(ap + 32);
    }

    int coff = e8 * 1024 + w * 256;
    const unsigned short* bp =
        V2b + ((size_t)kb * NSUB + coff + (l & 15)) * DIM + (q * 8);

    float m1[16], m2[16];
#pragma unroll
    for (int sl = 0; sl < 16; ++sl) { m1[sl] = 0.f; m2[sl] = 0.f; }

    bf16x8 cb0 = *(const bf16x8*)bp;
    bf16x8 cb1 = *(const bf16x8*)(bp + 32);
    bp += 16 * DIM;

    for (int s = 0; s < 16; ++s) {
        bf16x8 nb0, nb1;
        if (s < 15) {
            nb0 = *(const bf16x8*)bp;
            nb1 = *(const bf16x8*)(bp + 32);
            bp += 16 * DIM;
        }
#pragma unroll
        for (int t = 0; t < 4; ++t) {
            f32x4 acc = {0.f, 0.f, 0.f, 0.f};
            acc = __builtin_amdgcn_mfma_f32_16x16x32_bf16(a0[t], cb0, acc, 0, 0, 0);
            acc = __builtin_amdgcn_mfma_f32_16x16x32_bf16(a1[t], cb1, acc, 0, 0, 0);
#pragma unroll
            for (int r = 0; r < 4; ++r) {
                int sl = t * 4 + r;
                float v = acc[r];
                m2[sl] = __builtin_amdgcn_fmed3f(v, m1[sl], m2[sl]);
                m1[sl] = fmaxf(m1[sl], v);
            }
        }
        cb0 = nb0; cb1 = nb1;
    }

#pragma unroll
    for (int st = 1; st <= 8; st <<= 1) {
#pragma unroll
        for (int sl = 0; sl < 16; ++sl) {
            float o1 = __shfl_xor(m1[sl], st);
            float o2 = __shfl_xor(m2[sl], st);
            float nm1 = fmaxf(m1[sl], o1);
            float nm2 = fmaxf(fminf(m1[sl], o1), fmaxf(m2[sl], o2));
            m1[sl] = nm1; m2[sl] = nm2;
        }
    }
    if ((l & 15) == 0) {
        int gblk = h * 16 + e8 * 4 + w;
#pragma unroll
        for (int sl = 0; sl < 16; ++sl) {
            int rowg = r0 + (sl >> 2) * 16 + q * 4 + (sl & 3);
            uint2 vv;
            vv.x = __float_as_uint(m1[sl]);
            vv.y = __float_as_uint(m2[sl]);
            *(uint2*)&S1[(size_t)rowg * 64 + gblk * 2] = vv;
        }
    }
}

// -------------------------------------------------------------------------
// K3 (filter + folded threshold): Phase A: per wg, each wave bitonic-sorts
// 16 rows' 64 block-top-2 keys from S1 -> Lth (20th largest - margin) in
// LDS. Phase B: recompute scores (same geometry as stage1, double-buffered
// B), append every value >= Lth[row] via device-scope atomic (~27/row).
// NO folded refine (R9 post-mortem: concentrating latency-bound refine
// into 128 last-arriver wgs cost ~250 us; separate dispatch spreads it
// over 8192 waves). grid 1024, block 256.
// -------------------------------------------------------------------------
__global__ __launch_bounds__(256, 4) void k_filter(const unsigned short* __restrict__ V1b,
                                                   const unsigned short* __restrict__ V2b,
                                                   const unsigned int* __restrict__ S1,
                                                   unsigned int* __restrict__ cnt,
                                                   int* __restrict__ colsG) {
    __shared__ float Lsh[64];
    int tid = threadIdx.x;
    int l = tid & 63;
    int w = tid >> 6;
    int bx = blockIdx.x;
    int rt = bx >> 3;
    int h  = (bx >> 2) & 1;
    int e8 = bx & 3;
    int r0 = rt * 64;
    int i  = r0 >> 12;
    int n0 = r0 & (NSUB - 1);
    int kb = 2 * i + h;
    int q  = l >> 4;

    // ---- Phase A: thresholds (wave w -> rows r0+w*16 .. +15) ----
    for (int rr = 0; rr < 16; ++rr) {
        int rowg = r0 + w * 16 + rr;
        unsigned key = S1[(size_t)rowg * 64 + l];
#pragma unroll
        for (int k = 2; k <= 64; k <<= 1) {
#pragma unroll
            for (int j = k >> 1; j > 0; j >>= 1) {
                unsigned other = (unsigned)__shfl_xor((int)key, j);
                int ixj = l ^ j;
                bool up = ((l & k) == 0);
                bool keepMax = ((l > ixj) == up);
                key = keepMax ? umax(key, other) : umin(key, other);
            }
        }
        // ascending; 20th largest at lane 44
        if (l == 44) Lsh[w * 16 + rr] = fmaxf(__uint_as_float(key) - 0.006f, 1e-30f);
    }
    __syncthreads();

    // ---- Phase B: filter ----
    bf16x8 a0[4], a1[4];
#pragma unroll
    for (int t = 0; t < 4; ++t) {
        const unsigned short* ap =
            V1b + ((size_t)kb * NSUB + n0 + t * 16 + (l & 15)) * DIM + (q * 8);
        a0[t] = *(const bf16x8*)ap;
        a1[t] = *(const bf16x8*)(ap + 32);
    }

    float Lr[16];
#pragma unroll
    for (int sl = 0; sl < 16; ++sl)
        Lr[sl] = Lsh[(sl >> 2) * 16 + q * 4 + (sl & 3)];

    int coff = e8 * 1024 + w * 256;
    const unsigned short* bp =
        V2b + ((size_t)kb * NSUB + coff + (l & 15)) * DIM + (q * 8);

    bf16x8 cb0 = *(const bf16x8*)bp;
    bf16x8 cb1 = *(const bf16x8*)(bp + 32);
    bp += 16 * DIM;

    for (int s = 0; s < 16; ++s) {
        bf16x8 nb0, nb1;
        if (s < 15) {
            nb0 = *(const bf16x8*)bp;
            nb1 = *(const bf16x8*)(bp + 32);
            bp += 16 * DIM;
        }
        int c = h * 4096 + coff + s * 16 + (l & 15);
#pragma unroll
        for (int t = 0; t < 4; ++t) {
            f32x4 acc = {0.f, 0.f, 0.f, 0.f};
            acc = __builtin_amdgcn_mfma_f32_16x16x32_bf16(a0[t], cb0, acc, 0, 0, 0);
            acc = __builtin_amdgcn_mfma_f32_16x16x32_bf16(a1[t], cb1, acc, 0, 0, 0);
#pragma unroll
            for (int r = 0; r < 4; ++r) {
                int sl = t * 4 + r;
                if (acc[r] >= Lr[sl]) {
                    int rowg = r0 + t * 16 + q * 4 + r;
                    unsigned pos = atomicAdd(&cnt[rowg], 1u);
                    if (pos < CAND) colsG[(size_t)rowg * CAND + pos] = c;
                }
            }
        }
        cb0 = nb0; cb1 = nb1;
    }
}

// -------------------------------------------------------------------------
// K4 (refine, f64 exact): recompute candidates' scores (same serial d-order
// as all passing rounds), rank by (f64 value, lower-col), write top-20 +
// tanh. One wave per row -> 8192 waves (latency-bound gather needs TLP).
// grid 2048 x 256. (verified R5-R7)
// -------------------------------------------------------------------------
__global__ __launch_bounds__(256) void k_refine(const double* __restrict__ V1d,
                                                const double* __restrict__ V2d,
                                                const unsigned int* __restrict__ cnt,
                                                const int* __restrict__ colsG,
                                                int* __restrict__ outIdx,
                                                float* __restrict__ outVal) {
    int tid = threadIdx.x;
    int l = tid & 63, w = tid >> 6;
    int row = blockIdx.x * 4 + w;
    int i = row >> 12, n = row & (NSUB - 1);

    unsigned cn = cnt[row];
    if (cn > CAND) cn = CAND;
    bool valid = (unsigned)l < cn;
    int c = valid ? colsG[(size_t)row * CAND + l] : 0;
    int k = 2 * i + (c >> 12);
    int m = c & (NSUB - 1);

    const double* v1p = V1d + ((size_t)k * NSUB + n) * DIM;
    const double* v2p = V2d + ((size_t)k * NSUB + m) * DIM;
    double a = 0.0;
    for (int d = 0; d < DIM; ++d) a += v1p[d] * v2p[d];

    double av = a > 0.0 ? a : 0.0;
    u64 key = (((u64)__double_as_longlong(av)) & ~0x1FFFull) | (u64)(8191 - c);
    if (!valid) key = 0;

    int rank = 0;
    for (int jj = 0; jj < 64; ++jj) {
        u64 kj = (u64)__shfl((long long)key, jj);
        rank += (kj > key || (kj == key && jj < l)) ? 1 : 0;
    }
    if (valid && rank < KTOP) {
        float val = (av > 0.0) ? (float)tanh(3.0 * av) : 0.0f;
        outIdx[(size_t)row * KTOP + rank] = c;
        outVal[(size_t)row * KTOP + rank] = val;
    }
}

// -------------------------------------------------------------------------
// K5: fused zero + scatter. wg owns 4 contiguous rows (128 KB).
// grid 2048 x 256. (verified R4-R9)
// -------------------------------------------------------------------------
__global__ __launch_bounds__(256) void k_write(const int* __restrict__ outIdx,
                                               const float* __restrict__ outVal,
                                               float* __restrict__ out) {
    int t = threadIdx.x;
    size_t base = (size_t)blockIdx.x * 4 * NROW;
    float4 z = {0.f, 0.f, 0.f, 0.f};
    float4* o4 = (float4*)(out + base);
#pragma unroll
    for (int it = 0; it < 32; ++it) o4[it * 256 + t] = z;
    __syncthreads();
    if (t < 4 * KTOP) {
        int row = blockIdx.x * 4 + t / KTOP;
        int c = outIdx[(size_t)blockIdx.x * 4 * KTOP + t];
        float v = outVal[(size_t)blockIdx.x * 4 * KTOP + t];
        out[(size_t)row * NROW + c] = v;
    }
}

extern "C" void kernel_launch(void* const* d_in, const int* in_sizes, int n_in,
                              void* d_out, int out_size, void* d_ws, size_t ws_size,
                              hipStream_t stream) {
    // inputs: idx, emb1, emb2, w1, w2, b1, b2
    const float* emb1 = (const float*)d_in[1];
    const float* emb2 = (const float*)d_in[2];
    const float* w1   = (const float*)d_in[3];
    const float* w2   = (const float*)d_in[4];
    const float* b1   = (const float*)d_in[5];
    const float* b2   = (const float*)d_in[6];
    float* out = (float*)d_out;

    // staging in the head of d_out (24 MB of 256 MB); fully consumed by
    // k_refine before k_write overwrites everything.
    char* p = (char*)d_out;
    double*         V1d   = (double*)p;                                      // 0..8 MB
    double*         V2d   = (double*)(p + (size_t)8 * 1024 * 1024);          // 8..16 MB
    unsigned short* V1b   = (unsigned short*)(p + (size_t)16 * 1024 * 1024); // 16..18 MB
    unsigned short* V2b   = (unsigned short*)(p + (size_t)18 * 1024 * 1024); // 18..20 MB
    unsigned int*   S1    = (unsigned int*)(p + (size_t)20 * 1024 * 1024);   // 20..22 MB
    int*            colsG = (int*)(p + (size_t)22 * 1024 * 1024);            // 22..24 MB

    int*          outIdx = (int*)d_ws;
    float*        outVal = (float*)((char*)d_ws + (size_t)NROW * KTOP * sizeof(int));
    unsigned int* cntp   = (unsigned int*)((char*)d_ws + (size_t)2 * NROW * KTOP * sizeof(int));

    hipLaunchKernelGGL(k_compute_v, dim3(512), dim3(256), 0, stream,
                       emb1, w1, b1, emb2, w2, b2, V1d, V2d, V1b, V2b, cntp);
    hipLaunchKernelGGL(k_stage1, dim3(1024), dim3(256), 0, stream, V1b, V2b, S1);
    hipLaunchKernelGGL(k_filter, dim3(1024), dim3(256), 0, stream,
                       V1b, V2b, S1, cntp, colsG);
    hipLaunchKernelGGL(k_refine, dim3(2048), dim3(256), 0, stream,
                       V1d, V2d, cntp, colsG, outIdx, outVal);
    hipLaunchKernelGGL(k_write, dim3(2048), dim3(256), 0, stream,
                       outIdx, outVal, out);
}

// Round 11
// 421.399 us; speedup vs baseline: 1.5942x; 1.0141x over previous
//
#include <hip/hip_runtime.h>
#include <hip/hip_bf16.h>

#define NSUB 4096
#define DIM 64
#define NROW 8192
#define KTOP 20
#define CAND 64        // max survivors per row in filter pass

typedef unsigned long long u64;
typedef __attribute__((ext_vector_type(8))) short bf16x8;   // 8 bf16 = 4 VGPRs
typedef __attribute__((ext_vector_type(4))) float f32x4;

__device__ __forceinline__ unsigned umax(unsigned a, unsigned b) { return a > b ? a : b; }
__device__ __forceinline__ unsigned umin(unsigned a, unsigned b) { return a < b ? a : b; }

// -------------------------------------------------------------------------
// K1: V[k] = emb[k] @ w[k] + b[k], f64 accumulate from f32 inputs.
// Emits f64 row-major (exact refine) + bf16 row-major (MFMA passes).
// Also zeroes cnt[8192] (blocks 0..31). grid 512, block 256.
// (verified R3-R10)
// -------------------------------------------------------------------------
__global__ __launch_bounds__(256) void k_compute_v(
        const float* __restrict__ emb1, const float* __restrict__ w1,
        const float* __restrict__ b1,
        const float* __restrict__ emb2, const float* __restrict__ w2,
        const float* __restrict__ b2,
        double* __restrict__ V1d, double* __restrict__ V2d,
        unsigned short* __restrict__ V1b, unsigned short* __restrict__ V2b,
        unsigned int* __restrict__ cnt) {
    __shared__ alignas(16) float embS[64 * 64];
    __shared__ alignas(16) float wS[64 * 64];
    __shared__ float bS[64];

    int bx    = blockIdx.x;
    int tid   = threadIdx.x;

    // zero the filter-pass counters (visible to later dispatches by stream order)
    if (bx < 32) cnt[bx * 256 + tid] = 0u;

    int which = bx >> 8;
    int rem   = bx & 255;
    int k     = rem >> 6;
    int tile  = rem & 63;
    int n0    = tile * 64;

    const float* emb = which ? emb2 : emb1;
    const float* w   = which ? w2 : w1;
    const float* b   = which ? b2 : b1;
    double* Vd = which ? V2d : V1d;
    unsigned short* Vb = which ? V2b : V1b;

    const float* esrc = emb + ((size_t)k * NSUB + n0) * DIM;
    const float* wsrc = w + (size_t)k * DIM * DIM;
    for (int t = tid; t < 64 * 64; t += 256) { embS[t] = esrc[t]; wS[t] = wsrc[t]; }
    if (tid < 64) bS[tid] = b[k * 64 + tid];
    __syncthreads();

    int e    = tid & 63;
    int mrow = tid >> 6;

    double accs[16];
#pragma unroll
    for (int it = 0; it < 16; ++it) accs[it] = (double)bS[e];

    for (int dg = 0; dg < 16; ++dg) {
        double wv[4];
#pragma unroll
        for (int q = 0; q < 4; ++q) wv[q] = (double)wS[(dg * 4 + q) * 64 + e];
#pragma unroll
        for (int it = 0; it < 16; ++it) {
            float4 em = *(const float4*)&embS[(mrow * 16 + it) * 64 + dg * 4];
            accs[it] += (double)em.x * wv[0] + (double)em.y * wv[1]
                      + (double)em.z * wv[2] + (double)em.w * wv[3];
        }
    }

#pragma unroll
    for (int it = 0; it < 16; ++it) {
        size_t o = ((size_t)k * NSUB + n0 + mrow * 16 + it) * DIM + e;
        Vd[o] = accs[it];
        __hip_bfloat16 hv = __float2bfloat16((float)accs[it]);
        Vb[o] = *reinterpret_cast<unsigned short*>(&hv);
    }
}

// -------------------------------------------------------------------------
// K2 (stage1): per (row, 256-col block) top-2 of relu(scores), in registers.
// wg = 64 rows x 1024 cols: grid 1024 -> 4 wg/CU, 4 waves/SIMD. Each wave:
// 4 A-tiles (4x B reuse), one 256-col block in 16 strips of 16, register
// double-buffered B. Top-2 update = fmax + fmed3 (m1>=m2 invariant). One
// butterfly merge after the loop. No LDS, no barriers.
// Output S1[row][32 blocks][2] = f32 bit patterns of block top-2.
// (verified R9/R10)
// -------------------------------------------------------------------------
__global__ __launch_bounds__(256, 4) void k_stage1(const unsigned short* __restrict__ V1b,
                                                   const unsigned short* __restrict__ V2b,
                                                   unsigned int* __restrict__ S1) {
    int tid = threadIdx.x;
    int l = tid & 63;
    int w = tid >> 6;
    int bx = blockIdx.x;
    int rt = bx >> 3;
    int h  = (bx >> 2) & 1;
    int e8 = bx & 3;
    int r0 = rt * 64;
    int i  = r0 >> 12;
    int n0 = r0 & (NSUB - 1);
    int kb = 2 * i + h;
    int q  = l >> 4;

    bf16x8 a0[4], a1[4];
#pragma unroll
    for (int t = 0; t < 4; ++t) {
        const unsigned short* ap =
            V1b + ((size_t)kb * NSUB + n0 + t * 16 + (l & 15)) * DIM + (q * 8);
        a0[t] = *(const bf16x8*)ap;
        a1[t] = *(const bf16x8*)(ap + 32);
    }

    int coff = e8 * 1024 + w * 256;
    const unsigned short* bp =
        V2b + ((size_t)kb * NSUB + coff + (l & 15)) * DIM + (q * 8);

    float m1[16], m2[16];
#pragma unroll
    for (int sl = 0; sl < 16; ++sl) { m1[sl] = 0.f; m2[sl] = 0.f; }

    bf16x8 cb0 = *(const bf16x8*)bp;
    bf16x8 cb1 = *(const bf16x8*)(bp + 32);
    bp += 16 * DIM;

    for (int s = 0; s < 16; ++s) {
        bf16x8 nb0, nb1;
        if (s < 15) {
            nb0 = *(const bf16x8*)bp;
            nb1 = *(const bf16x8*)(bp + 32);
            bp += 16 * DIM;
        }
#pragma unroll
        for (int t = 0; t < 4; ++t) {
            f32x4 acc = {0.f, 0.f, 0.f, 0.f};
            acc = __builtin_amdgcn_mfma_f32_16x16x32_bf16(a0[t], cb0, acc, 0, 0, 0);
            acc = __builtin_amdgcn_mfma_f32_16x16x32_bf16(a1[t], cb1, acc, 0, 0, 0);
#pragma unroll
            for (int r = 0; r < 4; ++r) {
                int sl = t * 4 + r;
                float v = acc[r];
                m2[sl] = __builtin_amdgcn_fmed3f(v, m1[sl], m2[sl]);
                m1[sl] = fmaxf(m1[sl], v);
            }
        }
        cb0 = nb0; cb1 = nb1;
    }

#pragma unroll
    for (int st = 1; st <= 8; st <<= 1) {
#pragma unroll
        for (int sl = 0; sl < 16; ++sl) {
            float o1 = __shfl_xor(m1[sl], st);
            float o2 = __shfl_xor(m2[sl], st);
            float nm1 = fmaxf(m1[sl], o1);
            float nm2 = fmaxf(fminf(m1[sl], o1), fmaxf(m2[sl], o2));
            m1[sl] = nm1; m2[sl] = nm2;
        }
    }
    if ((l & 15) == 0) {
        int gblk = h * 16 + e8 * 4 + w;
#pragma unroll
        for (int sl = 0; sl < 16; ++sl) {
            int rowg = r0 + (sl >> 2) * 16 + q * 4 + (sl & 3);
            uint2 vv;
            vv.x = __float_as_uint(m1[sl]);
            vv.y = __float_as_uint(m2[sl]);
            *(uint2*)&S1[(size_t)rowg * 64 + gblk * 2] = vv;
        }
    }
}

// -------------------------------------------------------------------------
// K3 (filter + folded threshold): Phase A: per wg, each wave bitonic-sorts
// 16 rows' 64 block-top-2 keys from S1 -> Lth (20th largest - margin) in
// LDS. Phase B: recompute scores (same geometry as stage1, double-buffered
// B), append every value >= Lth[row] via device-scope atomic (~27/row).
// grid 1024, block 256. (verified R9/R10)
// -------------------------------------------------------------------------
__global__ __launch_bounds__(256, 4) void k_filter(const unsigned short* __restrict__ V1b,
                                                   const unsigned short* __restrict__ V2b,
                                                   const unsigned int* __restrict__ S1,
                                                   unsigned int* __restrict__ cnt,
                                                   int* __restrict__ colsG) {
    __shared__ float Lsh[64];
    int tid = threadIdx.x;
    int l = tid & 63;
    int w = tid >> 6;
    int bx = blockIdx.x;
    int rt = bx >> 3;
    int h  = (bx >> 2) & 1;
    int e8 = bx & 3;
    int r0 = rt * 64;
    int i  = r0 >> 12;
    int n0 = r0 & (NSUB - 1);
    int kb = 2 * i + h;
    int q  = l >> 4;

    // ---- Phase A: thresholds (wave w -> rows r0+w*16 .. +15) ----
    for (int rr = 0; rr < 16; ++rr) {
        int rowg = r0 + w * 16 + rr;
        unsigned key = S1[(size_t)rowg * 64 + l];
#pragma unroll
        for (int k = 2; k <= 64; k <<= 1) {
#pragma unroll
            for (int j = k >> 1; j > 0; j >>= 1) {
                unsigned other = (unsigned)__shfl_xor((int)key, j);
                int ixj = l ^ j;
                bool up = ((l & k) == 0);
                bool keepMax = ((l > ixj) == up);
                key = keepMax ? umax(key, other) : umin(key, other);
            }
        }
        // ascending; 20th largest at lane 44
        if (l == 44) Lsh[w * 16 + rr] = fmaxf(__uint_as_float(key) - 0.006f, 1e-30f);
    }
    __syncthreads();

    // ---- Phase B: filter ----
    bf16x8 a0[4], a1[4];
#pragma unroll
    for (int t = 0; t < 4; ++t) {
        const unsigned short* ap =
            V1b + ((size_t)kb * NSUB + n0 + t * 16 + (l & 15)) * DIM + (q * 8);
        a0[t] = *(const bf16x8*)ap;
        a1[t] = *(const bf16x8*)(ap + 32);
    }

    float Lr[16];
#pragma unroll
    for (int sl = 0; sl < 16; ++sl)
        Lr[sl] = Lsh[(sl >> 2) * 16 + q * 4 + (sl & 3)];

    int coff = e8 * 1024 + w * 256;
    const unsigned short* bp =
        V2b + ((size_t)kb * NSUB + coff + (l & 15)) * DIM + (q * 8);

    bf16x8 cb0 = *(const bf16x8*)bp;
    bf16x8 cb1 = *(const bf16x8*)(bp + 32);
    bp += 16 * DIM;

    for (int s = 0; s < 16; ++s) {
        bf16x8 nb0, nb1;
        if (s < 15) {
            nb0 = *(const bf16x8*)bp;
            nb1 = *(const bf16x8*)(bp + 32);
            bp += 16 * DIM;
        }
        int c = h * 4096 + coff + s * 16 + (l & 15);
#pragma unroll
        for (int t = 0; t < 4; ++t) {
            f32x4 acc = {0.f, 0.f, 0.f, 0.f};
            acc = __builtin_amdgcn_mfma_f32_16x16x32_bf16(a0[t], cb0, acc, 0, 0, 0);
            acc = __builtin_amdgcn_mfma_f32_16x16x32_bf16(a1[t], cb1, acc, 0, 0, 0);
#pragma unroll
            for (int r = 0; r < 4; ++r) {
                int sl = t * 4 + r;
                if (acc[r] >= Lr[sl]) {
                    int rowg = r0 + t * 16 + q * 4 + r;
                    unsigned pos = atomicAdd(&cnt[rowg], 1u);
                    if (pos < CAND) colsG[(size_t)rowg * CAND + pos] = c;
                }
            }
        }
        cb0 = nb0; cb1 = nb1;
    }
}

// -------------------------------------------------------------------------
// K4 (zero + refine + scatter, fused): wg owns 4 contiguous output rows.
// (1) 128 KB of vectorized zero stores for those rows; (2) concurrently,
// wave w refines row 4*bx+w: exact f64 dots over <=64 candidates (same
// serial d-order as all passing rounds), rank by (f64 value, lower-col);
// (3) barrier (drains zero stores), lanes with rank<20 store tanh values
// directly into this wg's own rows. All staging lives in d_ws, so zeroing
// d_out races with nothing. grid 2048 x 256.
// -------------------------------------------------------------------------
__global__ __launch_bounds__(256) void k_write(const double* __restrict__ V1d,
                                               const double* __restrict__ V2d,
                                               const unsigned int* __restrict__ cnt,
                                               const int* __restrict__ colsG,
                                               float* __restrict__ out) {
    int t = threadIdx.x;
    int l = t & 63, w = t >> 6;
    size_t base = (size_t)blockIdx.x * 4 * NROW;
    float4 z = {0.f, 0.f, 0.f, 0.f};
    float4* o4 = (float4*)(out + base);
#pragma unroll
    for (int it = 0; it < 32; ++it) o4[it * 256 + t] = z;

    // ---- refine (overlaps with the zero-store drain) ----
    int row = blockIdx.x * 4 + w;
    int i = row >> 12, n = row & (NSUB - 1);

    unsigned cn = cnt[row];
    if (cn > CAND) cn = CAND;
    bool valid = (unsigned)l < cn;
    int c = valid ? colsG[(size_t)row * CAND + l] : 0;
    int k = 2 * i + (c >> 12);
    int m = c & (NSUB - 1);

    const double* v1p = V1d + ((size_t)k * NSUB + n) * DIM;
    const double* v2p = V2d + ((size_t)k * NSUB + m) * DIM;
    double a = 0.0;
    for (int d = 0; d < DIM; ++d) a += v1p[d] * v2p[d];

    double av = a > 0.0 ? a : 0.0;
    u64 key = (((u64)__double_as_longlong(av)) & ~0x1FFFull) | (u64)(8191 - c);
    if (!valid) key = 0;

    int rank = 0;
    for (int jj = 0; jj < 64; ++jj) {
        u64 kj = (u64)__shfl((long long)key, jj);
        rank += (kj > key || (kj == key && jj < l)) ? 1 : 0;
    }

    __syncthreads();   // zero stores for this wg's rows complete

    if (valid && rank < KTOP) {
        float val = (av > 0.0) ? (float)tanh(3.0 * av) : 0.0f;
        out[(size_t)row * NROW + c] = val;
    }
}

extern "C" void kernel_launch(void* const* d_in, const int* in_sizes, int n_in,
                              void* d_out, int out_size, void* d_ws, size_t ws_size,
                              hipStream_t stream) {
    // inputs: idx, emb1, emb2, w1, w2, b1, b2
    const float* emb1 = (const float*)d_in[1];
    const float* emb2 = (const float*)d_in[2];
    const float* w1   = (const float*)d_in[3];
    const float* w2   = (const float*)d_in[4];
    const float* b1   = (const float*)d_in[5];
    const float* b2   = (const float*)d_in[6];
    float* out = (float*)d_out;

    // ALL staging in d_ws (1 GiB per the harness poison fill; we use 24 MB).
    // d_out is write-only -> the fused zero+refine kernel races with nothing.
    char* p = (char*)d_ws;
    double*         V1d   = (double*)p;                                      // 0..8 MB
    double*         V2d   = (double*)(p + (size_t)8 * 1024 * 1024);          // 8..16 MB
    unsigned short* V1b   = (unsigned short*)(p + (size_t)16 * 1024 * 1024); // 16..18 MB
    unsigned short* V2b   = (unsigned short*)(p + (size_t)18 * 1024 * 1024); // 18..20 MB
    unsigned int*   S1    = (unsigned int*)(p + (size_t)20 * 1024 * 1024);   // 20..22 MB
    int*            colsG = (int*)(p + (size_t)22 * 1024 * 1024);            // 22..24 MB
    unsigned int*   cntp  = (unsigned int*)(p + (size_t)24 * 1024 * 1024);   // 32 KB

    hipLaunchKernelGGL(k_compute_v, dim3(512), dim3(256), 0, stream,
                       emb1, w1, b1, emb2, w2, b2, V1d, V2d, V1b, V2b, cntp);
    hipLaunchKernelGGL(k_stage1, dim3(1024), dim3(256), 0, stream, V1b, V2b, S1);
    hipLaunchKernelGGL(k_filter, dim3(1024), dim3(256), 0, stream,
                       V1b, V2b, S1, cntp, colsG);
    hipLaunchKernelGGL(k_write, dim3(2048), dim3(256), 0, stream,
                       V1d, V2d, cntp, colsG, out);
}